// Round 1
// baseline (1763.144 us; speedup 1.0000x reference)
//
#include <hip/hip_runtime.h>
#include <math.h>

// ---------------------------------------------------------------------------
// DQNNet (GraphSAGE-like GNN), fp32 end-to-end.
//   h = l2norm(relu(x @ W1^T + b1))
//   2x: nm = segment_sum(h[src], dst);  h = l2norm(relu([h@W2^T+b2 | nm@W3^T+b3]))
//   h = relu(h @ Wd1^T + bd1);  out = h @ Wd2^T + bd2
// ---------------------------------------------------------------------------

constexpr int DIM = 256;
constexpr int BM = 128;   // rows per block
constexpr int BN = 256;   // full output width per block (enables fused l2norm)
constexpr int BK = 32;    // K-tile

// Fused GEMM: out[m, 0:128)  = A1[m,:] @ WA^T + bA   (WA is [128,256])
//             out[m,128:256) = A2[m,:] @ WB^T + bB   (WB is [128,256])
// then relu, then (optionally) row-wise l2 normalization.
// Single-matrix layers pass A2=A1, WA=W, WB=W+128*256, bB=b+128.
// In-place (out aliasing A1/A2) is safe: each block reads only its own rows.
template <int DO_NORM>
__global__ __launch_bounds__(256, 2)
void gemm_fused(const float* __restrict__ A1, const float* __restrict__ A2,
                const float* __restrict__ WA, const float* __restrict__ WB,
                const float* __restrict__ bA, const float* __restrict__ bB,
                float* __restrict__ out, int M)
{
    // LDS: transposed tiles. As*[k][r], Ws[k][n]. 16K floats = 64 KB.
    __shared__ float smem[BK * BM * 2 + BK * BN];
    float* As1 = smem;                 // [32][128]
    float* As2 = smem + BK * BM;       // [32][128]
    float* Ws  = smem + 2 * BK * BM;   // [32][256]

    const int tid = threadIdx.x;
    const int rg  = tid & 15;          // row group: rows rg*4..+3 and 64+rg*4..+3
    const int cg  = tid >> 4;          // col group: cols cg*16..+15
    const int n0  = cg * 16;
    const int bm0 = blockIdx.x * BM;

    float acc[8][16];
    #pragma unroll
    for (int i = 0; i < 8; ++i)
        #pragma unroll
        for (int j = 0; j < 16; ++j) acc[i][j] = 0.0f;

    const int lrow   = tid >> 3;       // 0..31 (staging row within 32-row strip)
    const int lchunk = tid & 7;        // 0..7  (k-chunk of 4 floats)

    #pragma unroll 1
    for (int t = 0; t < DIM / BK; ++t) {
        const int k0 = t * BK;
        // stage A1/A2 tiles: BM x BK, 4 float4 per thread each, transposed store
        #pragma unroll
        for (int l = 0; l < 4; ++l) {
            const int r  = lrow + l * 32;
            const int gr = bm0 + r;
            float4 v1 = {0.f, 0.f, 0.f, 0.f}, v2 = {0.f, 0.f, 0.f, 0.f};
            if (gr < M) {
                v1 = *(const float4*)&A1[(size_t)gr * DIM + k0 + lchunk * 4];
                v2 = *(const float4*)&A2[(size_t)gr * DIM + k0 + lchunk * 4];
            }
            As1[(lchunk * 4 + 0) * BM + r] = v1.x;
            As1[(lchunk * 4 + 1) * BM + r] = v1.y;
            As1[(lchunk * 4 + 2) * BM + r] = v1.z;
            As1[(lchunk * 4 + 3) * BM + r] = v1.w;
            As2[(lchunk * 4 + 0) * BM + r] = v2.x;
            As2[(lchunk * 4 + 1) * BM + r] = v2.y;
            As2[(lchunk * 4 + 2) * BM + r] = v2.z;
            As2[(lchunk * 4 + 3) * BM + r] = v2.w;
        }
        // stage W tile: BN x BK, 8 float4 per thread, transposed store
        #pragma unroll
        for (int l = 0; l < 8; ++l) {
            const int n = lrow + l * 32;
            const float* wsrc = (n < 128) ? &WA[(size_t)n * DIM]
                                          : &WB[(size_t)(n - 128) * DIM];
            float4 v = *(const float4*)&wsrc[k0 + lchunk * 4];
            Ws[(lchunk * 4 + 0) * BN + n] = v.x;
            Ws[(lchunk * 4 + 1) * BN + n] = v.y;
            Ws[(lchunk * 4 + 2) * BN + n] = v.z;
            Ws[(lchunk * 4 + 3) * BN + n] = v.w;
        }
        __syncthreads();

        const float* As = (cg < 8) ? As1 : As2;   // cols<128 read A1, cols>=128 read A2
        #pragma unroll 4
        for (int k = 0; k < BK; ++k) {
            const float4 alo = *(const float4*)&As[k * BM + rg * 4];
            const float4 ahi = *(const float4*)&As[k * BM + 64 + rg * 4];
            const float4 w0  = *(const float4*)&Ws[k * BN + n0];
            const float4 w1  = *(const float4*)&Ws[k * BN + n0 + 4];
            const float4 w2  = *(const float4*)&Ws[k * BN + n0 + 8];
            const float4 w3  = *(const float4*)&Ws[k * BN + n0 + 12];
            const float a_[8]  = {alo.x, alo.y, alo.z, alo.w, ahi.x, ahi.y, ahi.z, ahi.w};
            const float b_[16] = {w0.x, w0.y, w0.z, w0.w, w1.x, w1.y, w1.z, w1.w,
                                  w2.x, w2.y, w2.z, w2.w, w3.x, w3.y, w3.z, w3.w};
            #pragma unroll
            for (int i = 0; i < 8; ++i)
                #pragma unroll
                for (int j = 0; j < 16; ++j)
                    acc[i][j] = fmaf(a_[i], b_[j], acc[i][j]);
        }
        __syncthreads();
    }

    // bias + relu
    float bias[16];
    #pragma unroll
    for (int j = 0; j < 16; ++j)
        bias[j] = (cg < 8) ? bA[n0 + j] : bB[n0 + j - 128];
    #pragma unroll
    for (int i = 0; i < 8; ++i)
        #pragma unroll
        for (int j = 0; j < 16; ++j)
            acc[i][j] = fmaxf(acc[i][j] + bias[j], 0.0f);

    if (DO_NORM) {
        float* red = smem;   // [BM][16] partial sums of squares (reuse As1 space)
        #pragma unroll
        for (int i = 0; i < 8; ++i) {
            const int r = (i < 4) ? rg * 4 + i : 64 + rg * 4 + (i - 4);
            float ss = 0.f;
            #pragma unroll
            for (int j = 0; j < 16; ++j) ss += acc[i][j] * acc[i][j];
            red[r * 16 + cg] = ss;
        }
        __syncthreads();
        #pragma unroll
        for (int i = 0; i < 8; ++i) {
            const int r = (i < 4) ? rg * 4 + i : 64 + rg * 4 + (i - 4);
            float tot = 0.f;
            #pragma unroll
            for (int c = 0; c < 16; ++c) tot += red[r * 16 + c];
            const float inv = 1.0f / sqrtf(tot);
            #pragma unroll
            for (int j = 0; j < 16; ++j) acc[i][j] *= inv;
        }
    }

    #pragma unroll
    for (int i = 0; i < 8; ++i) {
        const int r  = (i < 4) ? rg * 4 + i : 64 + rg * 4 + (i - 4);
        const int gr = bm0 + r;
        if (gr < M) {
            #pragma unroll
            for (int j4 = 0; j4 < 4; ++j4) {
                float4 v = {acc[i][j4 * 4], acc[i][j4 * 4 + 1],
                            acc[i][j4 * 4 + 2], acc[i][j4 * 4 + 3]};
                *(float4*)&out[(size_t)gr * DIM + n0 + j4 * 4] = v;
            }
        }
    }
}

// ------------------------- CSR build -------------------------

__global__ void hist_kernel(const int* __restrict__ ei, int E, int* __restrict__ cnt)
{
    int e = blockIdx.x * blockDim.x + threadIdx.x;
    if (e < E) atomicAdd(&cnt[ei[E + e]], 1);
}

__global__ void scan1_kernel(const int* __restrict__ cnt, int n,
                             int* __restrict__ rp, int* __restrict__ sums)
{
    __shared__ int sm[1024];
    const int tid = threadIdx.x;
    const int i = blockIdx.x * 1024 + tid;
    const int v = (i < n) ? cnt[i] : 0;
    sm[tid] = v;
    __syncthreads();
    for (int off = 1; off < 1024; off <<= 1) {
        int t = (tid >= off) ? sm[tid - off] : 0;
        __syncthreads();
        sm[tid] += t;
        __syncthreads();
    }
    if (i < n) rp[i] = sm[tid] - v;          // exclusive (block-local)
    if (tid == 1023) sums[blockIdx.x] = sm[tid];
}

__global__ void scan2_kernel(int* __restrict__ sums, int n)
{
    __shared__ int sm[128];
    const int tid = threadIdx.x;
    const int v = (tid < n) ? sums[tid] : 0;
    sm[tid] = v;
    __syncthreads();
    for (int off = 1; off < 128; off <<= 1) {
        int t = (tid >= off) ? sm[tid - off] : 0;
        __syncthreads();
        sm[tid] += t;
        __syncthreads();
    }
    if (tid < n) sums[tid] = sm[tid] - v;    // exclusive
}

__global__ void scan3_kernel(int* __restrict__ rp, const int* __restrict__ sums,
                             int* __restrict__ cursor, int n, int E)
{
    int i = blockIdx.x * blockDim.x + threadIdx.x;
    if (i < n) {
        int v = rp[i] + sums[i >> 10];
        rp[i] = v;
        cursor[i] = v;
    }
    if (i == 0) rp[n] = E;
}

__global__ void fill_kernel(const int* __restrict__ ei, int E,
                            int* __restrict__ cursor, int* __restrict__ esrc)
{
    int e = blockIdx.x * blockDim.x + threadIdx.x;
    if (e < E) {
        int d = ei[E + e];
        int p = atomicAdd(&cursor[d], 1);
        esrc[p] = ei[e];
    }
}

// ------------------------- aggregation: one wave per node -------------------------

__global__ void agg_kernel(const float* __restrict__ h, const int* __restrict__ rp,
                           const int* __restrict__ esrc, float* __restrict__ nm, int M)
{
    const int gid = blockIdx.x * blockDim.x + threadIdx.x;
    const int v = gid >> 6;
    const int lane = gid & 63;
    if (v >= M) return;
    const int beg = rp[v], end = rp[v + 1];
    float4 acc = {0.f, 0.f, 0.f, 0.f};
    for (int j = beg; j < end; ++j) {
        const int s = esrc[j];
        const float4 hv = *(const float4*)&h[(size_t)s * DIM + lane * 4];
        acc.x += hv.x; acc.y += hv.y; acc.z += hv.z; acc.w += hv.w;
    }
    *(float4*)&nm[(size_t)v * DIM + lane * 4] = acc;
}

// ------------------------- final matvec: out = h @ Wd2^T + bd2 -------------------------

__global__ void matvec_kernel(const float* __restrict__ h, const float* __restrict__ w,
                              const float* __restrict__ b, float* __restrict__ out, int M)
{
    const int gid = blockIdx.x * blockDim.x + threadIdx.x;
    const int row = gid >> 6;
    const int lane = gid & 63;
    if (row >= M) return;
    const float4 hv = *(const float4*)&h[(size_t)row * DIM + lane * 4];
    const float4 wv = *(const float4*)&w[lane * 4];
    float s = hv.x * wv.x + hv.y * wv.y + hv.z * wv.z + hv.w * wv.w;
    #pragma unroll
    for (int off = 32; off > 0; off >>= 1) s += __shfl_down(s, off);
    if (lane == 0) out[row] = s + b[0];
}

// ------------------------- launch -------------------------

extern "C" void kernel_launch(void* const* d_in, const int* in_sizes, int n_in,
                              void* d_out, int out_size, void* d_ws, size_t ws_size,
                              hipStream_t stream)
{
    const float* x   = (const float*)d_in[0];
    const int*   ei  = (const int*)d_in[1];
    const float* W1  = (const float*)d_in[2];
    const float* b1  = (const float*)d_in[3];
    const float* W2  = (const float*)d_in[4];
    const float* b2  = (const float*)d_in[5];
    const float* W3  = (const float*)d_in[6];
    const float* b3  = (const float*)d_in[7];
    const float* Wd1 = (const float*)d_in[8];
    const float* bd1 = (const float*)d_in[9];
    const float* Wd2 = (const float*)d_in[10];
    const float* bd2 = (const float*)d_in[11];
    float* out = (float*)d_out;

    const int M = in_sizes[0] / DIM;   // 100000 nodes
    const int E = in_sizes[1] / 2;     // 1600000 edges

    // workspace layout
    float* h      = (float*)d_ws;                 // M*256 f32
    float* nm     = h + (size_t)M * DIM;          // M*256 f32
    int*   rp     = (int*)(nm + (size_t)M * DIM); // M+1
    int*   cursor = rp + (M + 1);                 // M
    int*   esrc   = cursor + M;                   // E
    int*   sums   = esrc + E;                     // scan block sums (<=128)

    hipMemsetAsync(cursor, 0, sizeof(int) * M, stream);

    const int gb = (M + BM - 1) / BM;
    const int eb = (E + 255) / 256;
    const int nb1 = (M + 1023) / 1024;
    const int wb = (M * 64 + 255) / 256;   // one wave per node/row

    // layer 1
    gemm_fused<1><<<gb, 256, 0, stream>>>(x, x, W1, W1 + 128 * DIM, b1, b1 + 128, h, M);

    // CSR build (done every call; inputs identical each call)
    hist_kernel<<<eb, 256, 0, stream>>>(ei, E, cursor);
    scan1_kernel<<<nb1, 1024, 0, stream>>>(cursor, M, rp, sums);
    scan2_kernel<<<1, 128, 0, stream>>>(sums, nb1);
    scan3_kernel<<<(M + 255) / 256, 256, 0, stream>>>(rp, sums, cursor, M, E);
    fill_kernel<<<eb, 256, 0, stream>>>(ei, E, cursor, esrc);

    // 2 message-passing layers
    for (int it = 0; it < 2; ++it) {
        agg_kernel<<<wb, 256, 0, stream>>>(h, rp, esrc, nm, M);
        gemm_fused<1><<<gb, 256, 0, stream>>>(h, nm, W2, W3, b2, b3, h, M);
    }

    // dense head
    gemm_fused<0><<<gb, 256, 0, stream>>>(h, h, Wd1, Wd1 + 128 * DIM, bd1, bd1 + 128, h, M);
    matvec_kernel<<<wb, 256, 0, stream>>>(h, Wd2, bd2, out, M);
}

// Round 2
// 1339.773 us; speedup vs baseline: 1.3160x; 1.3160x over previous
//
#include <hip/hip_runtime.h>
#include <math.h>

// ---------------------------------------------------------------------------
// DQNNet (GraphSAGE-like GNN), fp32 end-to-end.
//   h = l2norm(relu(x @ W1^T + b1))
//   2x: z = h @ [W2;W3]^T   (linearity: agg AFTER the GEMM, on the W3-half)
//       h = l2norm(relu([z1 + b2 | segsum(z2[src]) + b3]))
//   out = relu(h @ Wd1^T + bd1) @ Wd2^T + bd2   (matvec fused into GEMM epilogue)
// ---------------------------------------------------------------------------

constexpr int DIM = 256;
constexpr int BM  = 128;   // rows per block
constexpr int BN  = 256;   // full output width per block
constexpr int BK  = 32;    // K-tile
constexpr int BMP = 132;   // padded LDS leading dims (multiple of 4 for b128-aligned
constexpr int BNP = 260;   //   reads; %8==4 so transposed stores are 4-way not 8-way)

// Single-A fused GEMM: out[m,n] = A[m,:] . Wrow(n) + bias[n], n in [0,256).
// Wrow(n) = WA[n] for n<128 else WB[n-128] (two [128,256] row-major blocks).
// BIAS_RELU: add bias + relu.  DO_NORM: row l2-normalize.  DO_HEAD: instead of
// storing rows, dot each row with wd2[256] and write scalar out1[m] + bd2.
template <int BIAS_RELU, int DO_NORM, int DO_HEAD>
__global__ __launch_bounds__(256, 2)
void gemm_fused(const float* __restrict__ A,
                const float* __restrict__ WA, const float* __restrict__ WB,
                const float* __restrict__ bA, const float* __restrict__ bB,
                float* __restrict__ out,
                const float* __restrict__ wd2, const float* __restrict__ bd2,
                float* __restrict__ out1, int M)
{
    __shared__ float smem[BK * BMP + BK * BNP];   // 4224 + 8320 floats = 50.2 KB
    float* As = smem;             // transposed [k][r], row stride BMP
    float* Ws = smem + BK * BMP;  // transposed [k][n], row stride BNP

    const int tid = threadIdx.x;
    const int rg  = tid & 15;          // rows rg*4..+3 and 64+rg*4..+3
    const int cg  = tid >> 4;          // cols cg*16..+15
    const int n0  = cg * 16;
    const int bm0 = blockIdx.x * BM;

    const int lrow   = tid >> 3;       // 0..31 (staging row within 32-strip)
    const int lchunk = tid & 7;        // 0..7  (k-chunk of 4 floats)

    float acc[8][16];
    #pragma unroll
    for (int i = 0; i < 8; ++i)
        #pragma unroll
        for (int j = 0; j < 16; ++j) acc[i][j] = 0.0f;

    float4 pa[4];   // prefetch regs: A tile (4 rows/thread), W tile (8 rows/thread)
    float4 pw[8];

    // --- prefetch tile 0 ---
    {
        const int k0 = 0;
        #pragma unroll
        for (int l = 0; l < 4; ++l) {
            const int gr = bm0 + lrow + l * 32;
            pa[l] = (gr < M) ? *(const float4*)&A[(size_t)gr * DIM + k0 + lchunk * 4]
                             : float4{0.f, 0.f, 0.f, 0.f};
        }
        #pragma unroll
        for (int l = 0; l < 8; ++l) {
            const int n = lrow + l * 32;
            const float* wsrc = (n < 128) ? &WA[(size_t)n * DIM]
                                          : &WB[(size_t)(n - 128) * DIM];
            pw[l] = *(const float4*)&wsrc[k0 + lchunk * 4];
        }
    }

    #pragma unroll 1
    for (int t = 0; t < DIM / BK; ++t) {
        // store prefetched tile into LDS (transposed; BMP/BNP pads -> 4-way max)
        #pragma unroll
        for (int l = 0; l < 4; ++l) {
            const int r = lrow + l * 32;
            As[(lchunk * 4 + 0) * BMP + r] = pa[l].x;
            As[(lchunk * 4 + 1) * BMP + r] = pa[l].y;
            As[(lchunk * 4 + 2) * BMP + r] = pa[l].z;
            As[(lchunk * 4 + 3) * BMP + r] = pa[l].w;
        }
        #pragma unroll
        for (int l = 0; l < 8; ++l) {
            const int n = lrow + l * 32;
            Ws[(lchunk * 4 + 0) * BNP + n] = pw[l].x;
            Ws[(lchunk * 4 + 1) * BNP + n] = pw[l].y;
            Ws[(lchunk * 4 + 2) * BNP + n] = pw[l].z;
            Ws[(lchunk * 4 + 3) * BNP + n] = pw[l].w;
        }
        __syncthreads();

        // issue global loads for NEXT tile now; ~8K cycles of FMA below hide them
        if (t < DIM / BK - 1) {
            const int k0 = (t + 1) * BK;
            #pragma unroll
            for (int l = 0; l < 4; ++l) {
                const int gr = bm0 + lrow + l * 32;
                pa[l] = (gr < M) ? *(const float4*)&A[(size_t)gr * DIM + k0 + lchunk * 4]
                                 : float4{0.f, 0.f, 0.f, 0.f};
            }
            #pragma unroll
            for (int l = 0; l < 8; ++l) {
                const int n = lrow + l * 32;
                const float* wsrc = (n < 128) ? &WA[(size_t)n * DIM]
                                              : &WB[(size_t)(n - 128) * DIM];
                pw[l] = *(const float4*)&wsrc[k0 + lchunk * 4];
            }
        }

        #pragma unroll 4
        for (int k = 0; k < BK; ++k) {
            const float4 alo = *(const float4*)&As[k * BMP + rg * 4];
            const float4 ahi = *(const float4*)&As[k * BMP + 64 + rg * 4];
            const float4 w0  = *(const float4*)&Ws[k * BNP + n0];
            const float4 w1  = *(const float4*)&Ws[k * BNP + n0 + 4];
            const float4 w2  = *(const float4*)&Ws[k * BNP + n0 + 8];
            const float4 w3  = *(const float4*)&Ws[k * BNP + n0 + 12];
            const float a_[8]  = {alo.x, alo.y, alo.z, alo.w, ahi.x, ahi.y, ahi.z, ahi.w};
            const float b_[16] = {w0.x, w0.y, w0.z, w0.w, w1.x, w1.y, w1.z, w1.w,
                                  w2.x, w2.y, w2.z, w2.w, w3.x, w3.y, w3.z, w3.w};
            #pragma unroll
            for (int i = 0; i < 8; ++i)
                #pragma unroll
                for (int j = 0; j < 16; ++j)
                    acc[i][j] = fmaf(a_[i], b_[j], acc[i][j]);
        }
        __syncthreads();
    }

    if (BIAS_RELU) {
        float bias[16];
        #pragma unroll
        for (int j = 0; j < 16; ++j)
            bias[j] = (cg < 8) ? bA[n0 + j] : bB[n0 + j - 128];
        #pragma unroll
        for (int i = 0; i < 8; ++i)
            #pragma unroll
            for (int j = 0; j < 16; ++j)
                acc[i][j] = fmaxf(acc[i][j] + bias[j], 0.0f);
    }

    if (DO_NORM) {
        float* red = smem;   // [BM][16] partial sums of squares
        #pragma unroll
        for (int i = 0; i < 8; ++i) {
            const int r = (i < 4) ? rg * 4 + i : 64 + rg * 4 + (i - 4);
            float ss = 0.f;
            #pragma unroll
            for (int j = 0; j < 16; ++j) ss += acc[i][j] * acc[i][j];
            red[r * 16 + cg] = ss;
        }
        __syncthreads();
        #pragma unroll
        for (int i = 0; i < 8; ++i) {
            const int r = (i < 4) ? rg * 4 + i : 64 + rg * 4 + (i - 4);
            float tot = 0.f;
            #pragma unroll
            for (int c = 0; c < 16; ++c) tot += red[r * 16 + c];
            const float inv = 1.0f / sqrtf(tot);
            #pragma unroll
            for (int j = 0; j < 16; ++j) acc[i][j] *= inv;
        }
    }

    if (DO_HEAD) {
        // fused final matvec: out1[m] = row . wd2 + bd2
        float wv[16];
        #pragma unroll
        for (int j = 0; j < 16; ++j) wv[j] = wd2[n0 + j];
        float* red = smem;
        #pragma unroll
        for (int i = 0; i < 8; ++i) {
            const int r = (i < 4) ? rg * 4 + i : 64 + rg * 4 + (i - 4);
            float d = 0.f;
            #pragma unroll
            for (int j = 0; j < 16; ++j) d += acc[i][j] * wv[j];
            red[r * 16 + cg] = d;
        }
        __syncthreads();
        if (cg == 0) {
            #pragma unroll
            for (int i = 0; i < 8; ++i) {
                const int r  = (i < 4) ? rg * 4 + i : 64 + rg * 4 + (i - 4);
                const int gr = bm0 + r;
                if (gr < M) {
                    float tot = 0.f;
                    #pragma unroll
                    for (int c = 0; c < 16; ++c) tot += red[r * 16 + c];
                    out1[gr] = tot + bd2[0];
                }
            }
        }
        return;
    }

    #pragma unroll
    for (int i = 0; i < 8; ++i) {
        const int r  = (i < 4) ? rg * 4 + i : 64 + rg * 4 + (i - 4);
        const int gr = bm0 + r;
        if (gr < M) {
            #pragma unroll
            for (int j4 = 0; j4 < 4; ++j4) {
                float4 v = {acc[i][j4 * 4], acc[i][j4 * 4 + 1],
                            acc[i][j4 * 4 + 2], acc[i][j4 * 4 + 3]};
                *(float4*)&out[(size_t)gr * DIM + n0 + j4 * 4] = v;
            }
        }
    }
}

// ------------------------- CSR build -------------------------

__global__ void hist_kernel(const int* __restrict__ ei, int E, int* __restrict__ cnt)
{
    int e = blockIdx.x * blockDim.x + threadIdx.x;
    if (e < E) atomicAdd(&cnt[ei[E + e]], 1);
}

__global__ void scan1_kernel(const int* __restrict__ cnt, int n,
                             int* __restrict__ rp, int* __restrict__ sums)
{
    __shared__ int sm[1024];
    const int tid = threadIdx.x;
    const int i = blockIdx.x * 1024 + tid;
    const int v = (i < n) ? cnt[i] : 0;
    sm[tid] = v;
    __syncthreads();
    for (int off = 1; off < 1024; off <<= 1) {
        int t = (tid >= off) ? sm[tid - off] : 0;
        __syncthreads();
        sm[tid] += t;
        __syncthreads();
    }
    if (i < n) rp[i] = sm[tid] - v;
    if (tid == 1023) sums[blockIdx.x] = sm[tid];
}

__global__ void scan2_kernel(int* __restrict__ sums, int n)
{
    __shared__ int sm[128];
    const int tid = threadIdx.x;
    const int v = (tid < n) ? sums[tid] : 0;
    sm[tid] = v;
    __syncthreads();
    for (int off = 1; off < 128; off <<= 1) {
        int t = (tid >= off) ? sm[tid - off] : 0;
        __syncthreads();
        sm[tid] += t;
        __syncthreads();
    }
    if (tid < n) sums[tid] = sm[tid] - v;
}

__global__ void scan3_kernel(int* __restrict__ rp, const int* __restrict__ sums,
                             int* __restrict__ cursor, int n, int E)
{
    int i = blockIdx.x * blockDim.x + threadIdx.x;
    if (i < n) {
        int v = rp[i] + sums[i >> 10];
        rp[i] = v;
        cursor[i] = v;
    }
    if (i == 0) rp[n] = E;
}

__global__ void fill_kernel(const int* __restrict__ ei, int E,
                            int* __restrict__ cursor, int* __restrict__ esrc)
{
    int e = blockIdx.x * blockDim.x + threadIdx.x;
    if (e < E) {
        int d = ei[E + e];
        int p = atomicAdd(&cursor[d], 1);
        esrc[p] = ei[e];
    }
}

// ---- finalize: h[v] = l2norm(relu([z1[v]+b2 | sum_{src->v} z2[src] + b3])) ----
// one wave per node; lane owns cols {2l, 2l+1} of each 128-wide half.
__global__ void fin_kernel(const float* __restrict__ z, const int* __restrict__ rp,
                           const int* __restrict__ esrc,
                           const float* __restrict__ b2, const float* __restrict__ b3,
                           float* __restrict__ h, int M)
{
    const int gid  = blockIdx.x * blockDim.x + threadIdx.x;
    const int v    = gid >> 6;
    const int lane = gid & 63;
    if (v >= M) return;
    const int beg = rp[v], end = rp[v + 1];

    float2 a0 = {0.f, 0.f}, a1 = {0.f, 0.f};
    int j = beg;
    for (; j + 1 < end; j += 2) {
        const int s0 = esrc[j], s1 = esrc[j + 1];
        const float2 g0 = *(const float2*)&z[(size_t)s0 * DIM + 128 + lane * 2];
        const float2 g1 = *(const float2*)&z[(size_t)s1 * DIM + 128 + lane * 2];
        a0.x += g0.x; a0.y += g0.y;
        a1.x += g1.x; a1.y += g1.y;
    }
    if (j < end) {
        const int s0 = esrc[j];
        const float2 g0 = *(const float2*)&z[(size_t)s0 * DIM + 128 + lane * 2];
        a0.x += g0.x; a0.y += g0.y;
    }
    a0.x += a1.x; a0.y += a1.y;

    const float2 z1 = *(const float2*)&z[(size_t)v * DIM + lane * 2];
    const float2 v2 = *(const float2*)&b2[lane * 2];
    const float2 v3 = *(const float2*)&b3[lane * 2];
    float u1x = fmaxf(z1.x + v2.x, 0.f), u1y = fmaxf(z1.y + v2.y, 0.f);
    float u2x = fmaxf(a0.x + v3.x, 0.f), u2y = fmaxf(a0.y + v3.y, 0.f);

    float ss = u1x * u1x + u1y * u1y + u2x * u2x + u2y * u2y;
    #pragma unroll
    for (int off = 32; off > 0; off >>= 1) ss += __shfl_xor(ss, off);
    const float inv = 1.0f / sqrtf(ss);

    float2 o1 = {u1x * inv, u1y * inv};
    float2 o2 = {u2x * inv, u2y * inv};
    *(float2*)&h[(size_t)v * DIM + lane * 2]       = o1;
    *(float2*)&h[(size_t)v * DIM + 128 + lane * 2] = o2;
}

// ------------------------- launch -------------------------

extern "C" void kernel_launch(void* const* d_in, const int* in_sizes, int n_in,
                              void* d_out, int out_size, void* d_ws, size_t ws_size,
                              hipStream_t stream)
{
    const float* x   = (const float*)d_in[0];
    const int*   ei  = (const int*)d_in[1];
    const float* W1  = (const float*)d_in[2];
    const float* b1  = (const float*)d_in[3];
    const float* W2  = (const float*)d_in[4];
    const float* b2  = (const float*)d_in[5];
    const float* W3  = (const float*)d_in[6];
    const float* b3  = (const float*)d_in[7];
    const float* Wd1 = (const float*)d_in[8];
    const float* bd1 = (const float*)d_in[9];
    const float* Wd2 = (const float*)d_in[10];
    const float* bd2 = (const float*)d_in[11];
    float* out = (float*)d_out;

    const int M = in_sizes[0] / DIM;   // 100000
    const int E = in_sizes[1] / 2;     // 1600000

    float* h      = (float*)d_ws;                 // M*256 f32
    float* z      = h + (size_t)M * DIM;          // M*256 f32
    int*   rp     = (int*)(z + (size_t)M * DIM);  // M+1
    int*   cursor = rp + (M + 1);                 // M
    int*   esrc   = cursor + M;                   // E
    int*   sums   = esrc + E;                     // <=128

    hipMemsetAsync(cursor, 0, sizeof(int) * M, stream);

    const int gb  = (M + BM - 1) / BM;
    const int eb  = (E + 255) / 256;
    const int nb1 = (M + 1023) / 1024;
    const int wb  = (M * 64 + 255) / 256;

    // CSR build
    hist_kernel<<<eb, 256, 0, stream>>>(ei, E, cursor);
    scan1_kernel<<<nb1, 1024, 0, stream>>>(cursor, M, rp, sums);
    scan2_kernel<<<1, 128, 0, stream>>>(sums, nb1);
    scan3_kernel<<<(M + 255) / 256, 256, 0, stream>>>(rp, sums, cursor, M, E);
    fill_kernel<<<eb, 256, 0, stream>>>(ei, E, cursor, esrc);

    // layer 1: h = l2norm(relu(x @ W1^T + b1))
    gemm_fused<1, 1, 0><<<gb, 256, 0, stream>>>(
        x, W1, W1 + 128 * DIM, b1, b1 + 128, h, nullptr, nullptr, nullptr, M);

    // 2 message-passing layers
    for (int it = 0; it < 2; ++it) {
        gemm_fused<0, 0, 0><<<gb, 256, 0, stream>>>(
            h, W2, W3, nullptr, nullptr, z, nullptr, nullptr, nullptr, M);
        fin_kernel<<<wb, 256, 0, stream>>>(z, rp, esrc, b2, b3, h, M);
    }

    // head: out = relu(h @ Wd1^T + bd1) @ Wd2^T + bd2 (matvec fused)
    gemm_fused<1, 0, 1><<<gb, 256, 0, stream>>>(
        h, Wd1, Wd1 + 128 * DIM, bd1, bd1 + 128, nullptr, Wd2, bd2, out, M);
}

// Round 3
// 872.391 us; speedup vs baseline: 2.0210x; 1.5357x over previous
//
#include <hip/hip_runtime.h>
#include <math.h>

// ---------------------------------------------------------------------------
// DQNNet GNN, f16x3 split-precision MFMA GEMMs (error ~2^-22, fp32-equivalent).
//   h = l2norm(relu(x @ W1^T + b1))            [gemm EPI=norm, A=fp32 split]
//   2x: z = h @ [W2;W3]^T                      [gemm EPI=z,   A=f16-pair]
//       h = l2norm(relu([z1+b2 | segsum(z2[src])+b3]))   [fin]
//   out = relu(h @ Wd1^T + bd1) @ Wd2^T + bd2  [gemm EPI=head, A=f16-pair]
// h stored as (hi,lo) f16 pairs packed in u32 (same bytes as fp32).
// ---------------------------------------------------------------------------

typedef _Float16 f16x8 __attribute__((ext_vector_type(8)));
typedef float    f32x16 __attribute__((ext_vector_type(16)));

constexpr int DIM = 256;
constexpr int BM  = 128;
constexpr int BK  = 32;    // K-slice per staged tile (f16 elements)
constexpr int SA  = 40;    // padded LDS row stride (f16): even bank spread
constexpr int SW  = 40;

__device__ __forceinline__ unsigned pk_hi2(float a, float b) {
    unsigned short ha = __builtin_bit_cast(unsigned short, (_Float16)a);
    unsigned short hb = __builtin_bit_cast(unsigned short, (_Float16)b);
    return (unsigned)ha | ((unsigned)hb << 16);
}
__device__ __forceinline__ unsigned pk_lo2(float a, float b) {
    _Float16 ha = (_Float16)a, hb = (_Float16)b;
    unsigned short la = __builtin_bit_cast(unsigned short, (_Float16)(a - (float)ha));
    unsigned short lb = __builtin_bit_cast(unsigned short, (_Float16)(b - (float)hb));
    return (unsigned)la | ((unsigned)lb << 16);
}
__device__ __forceinline__ unsigned pack_pair(float v) {
    _Float16 hi = (_Float16)v;
    _Float16 lo = (_Float16)(v - (float)hi);
    return (unsigned)__builtin_bit_cast(unsigned short, hi)
         | ((unsigned)__builtin_bit_cast(unsigned short, lo) << 16);
}

// AMODE: 0 = A is fp32 (split during staging); 1 = A is (hi,lo)-pair u32.
// EPI:   0 = write raw fp32 z; 1 = bias+relu+l2norm -> pair out; 2 = bias+relu+
//        fused matvec with wd2 -> scalar out1.
template <int AMODE, int EPI>
__global__ __launch_bounds__(256, 2)
void gemm_mfma(const void* __restrict__ Av,
               const float* __restrict__ WA, const float* __restrict__ WB,
               const float* __restrict__ bA, const float* __restrict__ bB,
               void* __restrict__ outv,
               const float* __restrict__ wd2, const float* __restrict__ bd2,
               float* __restrict__ out1, int M)
{
    // LDS: As_hi[128][40] As_lo[128][40] Ws_hi[256][40] Ws_lo[256][40] = 60 KB
    __shared__ __align__(16) _Float16 smem[30720];
    _Float16* As_hi = smem;
    _Float16* As_lo = smem + 5120;
    _Float16* Ws_hi = smem + 10240;
    _Float16* Ws_lo = smem + 20480;

    const int tid  = threadIdx.x;
    const int lane = tid & 63;
    const int w    = tid >> 6;
    const int rh   = w >> 1;           // wave row-half (rows rh*64..+64)
    const int ch   = w & 1;            // wave col-half (cols ch*128..+128)
    const int l31  = lane & 31;
    const int lh   = lane >> 5;        // k-group within fragment
    const int bm0  = blockIdx.x * BM;

    const unsigned* Au = (const unsigned*)Av;  // 4-B elems, row stride 256 both modes
    const int srow = tid >> 3;                 // staging base row
    const int sch  = (tid & 7) * 4;            // staging k-chunk (4 elems of 4 B)

    uint4  pa[4];
    float4 pw[8];

    auto fetchA = [&](int t) {
        const int k0 = t * BK;
        #pragma unroll
        for (int i = 0; i < 4; ++i) {
            const int gr = bm0 + srow + 32 * i;
            uint4 v = {0u, 0u, 0u, 0u};
            if (gr < M) v = *(const uint4*)&Au[(size_t)gr * 256 + k0 + sch];
            pa[i] = v;
        }
    };
    auto fetchW = [&](int t) {
        const int k0 = t * BK;
        #pragma unroll
        for (int i = 0; i < 8; ++i) {
            const int r = srow + 32 * i;
            const float* src = (r < 128) ? &WA[(size_t)r * 256]
                                         : &WB[(size_t)(r - 128) * 256];
            pw[i] = *(const float4*)&src[k0 + sch];
        }
    };
    auto stageA = [&]() {
        #pragma unroll
        for (int i = 0; i < 4; ++i) {
            const int r = srow + 32 * i;
            unsigned h0, h1, l0, l1;
            if (AMODE == 0) {
                const float x0 = __builtin_bit_cast(float, pa[i].x);
                const float x1 = __builtin_bit_cast(float, pa[i].y);
                const float x2 = __builtin_bit_cast(float, pa[i].z);
                const float x3 = __builtin_bit_cast(float, pa[i].w);
                h0 = pk_hi2(x0, x1); h1 = pk_hi2(x2, x3);
                l0 = pk_lo2(x0, x1); l1 = pk_lo2(x2, x3);
            } else {
                h0 = __builtin_amdgcn_perm(pa[i].y, pa[i].x, 0x05040100u);
                l0 = __builtin_amdgcn_perm(pa[i].y, pa[i].x, 0x07060302u);
                h1 = __builtin_amdgcn_perm(pa[i].w, pa[i].z, 0x05040100u);
                l1 = __builtin_amdgcn_perm(pa[i].w, pa[i].z, 0x07060302u);
            }
            uint2 th; th.x = h0; th.y = h1;
            uint2 tl; tl.x = l0; tl.y = l1;
            *(uint2*)&As_hi[r * SA + sch] = th;
            *(uint2*)&As_lo[r * SA + sch] = tl;
        }
    };
    auto stageW = [&]() {
        #pragma unroll
        for (int i = 0; i < 8; ++i) {
            const int r = srow + 32 * i;
            uint2 th; th.x = pk_hi2(pw[i].x, pw[i].y); th.y = pk_hi2(pw[i].z, pw[i].w);
            uint2 tl; tl.x = pk_lo2(pw[i].x, pw[i].y); tl.y = pk_lo2(pw[i].z, pw[i].w);
            *(uint2*)&Ws_hi[r * SW + sch] = th;
            *(uint2*)&Ws_lo[r * SW + sch] = tl;
        }
    };

    f32x16 acc[2][4];
    #pragma unroll
    for (int tr = 0; tr < 2; ++tr)
        #pragma unroll
        for (int tc = 0; tc < 4; ++tc)
            #pragma unroll
            for (int i = 0; i < 16; ++i) acc[tr][tc][i] = 0.0f;

    fetchA(0); fetchW(0);

    #pragma unroll 1
    for (int t = 0; t < DIM / BK; ++t) {
        stageA(); stageW();
        __syncthreads();
        if (t < DIM / BK - 1) { fetchA(t + 1); fetchW(t + 1); }

        #pragma unroll
        for (int ks = 0; ks < 2; ++ks) {
            f16x8 ah[2], al[2], wh[4], wl[4];
            #pragma unroll
            for (int tr = 0; tr < 2; ++tr) {
                const int off = (rh * 64 + tr * 32 + l31) * SA + ks * 16 + lh * 8;
                ah[tr] = *(const f16x8*)&As_hi[off];
                al[tr] = *(const f16x8*)&As_lo[off];
            }
            #pragma unroll
            for (int tc = 0; tc < 4; ++tc) {
                const int off = (ch * 128 + tc * 32 + l31) * SW + ks * 16 + lh * 8;
                wh[tc] = *(const f16x8*)&Ws_hi[off];
                wl[tc] = *(const f16x8*)&Ws_lo[off];
            }
            #pragma unroll
            for (int tr = 0; tr < 2; ++tr)
                #pragma unroll
                for (int tc = 0; tc < 4; ++tc) {
                    acc[tr][tc] = __builtin_amdgcn_mfma_f32_32x32x16_f16(ah[tr], wh[tc], acc[tr][tc], 0, 0, 0);
                    acc[tr][tc] = __builtin_amdgcn_mfma_f32_32x32x16_f16(ah[tr], wl[tc], acc[tr][tc], 0, 0, 0);
                    acc[tr][tc] = __builtin_amdgcn_mfma_f32_32x32x16_f16(al[tr], wh[tc], acc[tr][tc], 0, 0, 0);
                }
        }
        __syncthreads();
    }

    // C/D layout (32x32, verified m74/m101): col = lane&31, row = (reg&3) + 8*(reg>>2) + 4*(lane>>5)

    if (EPI == 0) {
        float* z = (float*)outv;
        #pragma unroll
        for (int tr = 0; tr < 2; ++tr)
            #pragma unroll
            for (int i = 0; i < 16; ++i) {
                const int r  = rh * 64 + tr * 32 + 4 * lh + (i & 3) + 8 * (i >> 2);
                const int gr = bm0 + r;
                if (gr < M) {
                    #pragma unroll
                    for (int tc = 0; tc < 4; ++tc)
                        z[(size_t)gr * 256 + ch * 128 + tc * 32 + l31] = acc[tr][tc][i];
                }
            }
        return;
    }

    // bias + relu
    {
        float bias[4];
        #pragma unroll
        for (int tc = 0; tc < 4; ++tc)
            bias[tc] = (ch ? bB : bA)[tc * 32 + l31];
        #pragma unroll
        for (int tr = 0; tr < 2; ++tr)
            #pragma unroll
            for (int tc = 0; tc < 4; ++tc)
                #pragma unroll
                for (int i = 0; i < 16; ++i)
                    acc[tr][tc][i] = fmaxf(acc[tr][tc][i] + bias[tc], 0.0f);
    }

    float* red = (float*)smem;   // [2 ch][128 rows], reuses LDS after final barrier

    if (EPI == 1) {
        // per-row sum of squares over this wave's 128 cols (butterfly in 32-lane half)
        float ss[2][16];
        #pragma unroll
        for (int tr = 0; tr < 2; ++tr)
            #pragma unroll
            for (int i = 0; i < 16; ++i) {
                float s = 0.f;
                #pragma unroll
                for (int tc = 0; tc < 4; ++tc) s += acc[tr][tc][i] * acc[tr][tc][i];
                #pragma unroll
                for (int m = 1; m < 32; m <<= 1) s += __shfl_xor(s, m);
                ss[tr][i] = s;
            }
        const int j  = l31;                 // lane writes entry (tr=j>>4, i=j&15)
        const int ji = j & 15, jt = j >> 4;
        red[ch * 128 + rh * 64 + jt * 32 + 4 * lh + (ji & 3) + 8 * (ji >> 2)] = ss[jt][ji];
        __syncthreads();

        unsigned* hp = (unsigned*)outv;
        #pragma unroll
        for (int tr = 0; tr < 2; ++tr)
            #pragma unroll
            for (int i = 0; i < 16; ++i) {
                const int rl = rh * 64 + tr * 32 + 4 * lh + (i & 3) + 8 * (i >> 2);
                const float inv = 1.0f / sqrtf(red[rl] + red[128 + rl]);
                const int gr = bm0 + rl;
                if (gr < M) {
                    #pragma unroll
                    for (int tc = 0; tc < 4; ++tc)
                        hp[(size_t)gr * 256 + ch * 128 + tc * 32 + l31] =
                            pack_pair(acc[tr][tc][i] * inv);
                }
            }
        return;
    }

    // EPI == 2: fused head matvec
    {
        float wv[4];
        #pragma unroll
        for (int tc = 0; tc < 4; ++tc) wv[tc] = wd2[ch * 128 + tc * 32 + l31];
        float dd[2][16];
        #pragma unroll
        for (int tr = 0; tr < 2; ++tr)
            #pragma unroll
            for (int i = 0; i < 16; ++i) {
                float s = 0.f;
                #pragma unroll
                for (int tc = 0; tc < 4; ++tc) s += acc[tr][tc][i] * wv[tc];
                #pragma unroll
                for (int m = 1; m < 32; m <<= 1) s += __shfl_xor(s, m);
                dd[tr][i] = s;
            }
        const int j  = l31;
        const int ji = j & 15, jt = j >> 4;
        red[ch * 128 + rh * 64 + jt * 32 + 4 * lh + (ji & 3) + 8 * (ji >> 2)] = dd[jt][ji];
        __syncthreads();
        if (tid < 128) {
            const int gr = bm0 + tid;
            if (gr < M) out1[gr] = red[tid] + red[128 + tid] + bd2[0];
        }
    }
}

// ------------------------- CSR build -------------------------

__global__ void hist_kernel(const int* __restrict__ ei, int E, int* __restrict__ cnt)
{
    int e = blockIdx.x * blockDim.x + threadIdx.x;
    if (e < E) atomicAdd(&cnt[ei[E + e]], 1);
}

__global__ void scan1_kernel(const int* __restrict__ cnt, int n,
                             int* __restrict__ rp, int* __restrict__ sums)
{
    __shared__ int sm[1024];
    const int tid = threadIdx.x;
    const int i = blockIdx.x * 1024 + tid;
    const int v = (i < n) ? cnt[i] : 0;
    sm[tid] = v;
    __syncthreads();
    for (int off = 1; off < 1024; off <<= 1) {
        int t = (tid >= off) ? sm[tid - off] : 0;
        __syncthreads();
        sm[tid] += t;
        __syncthreads();
    }
    if (i < n) rp[i] = sm[tid] - v;
    if (tid == 1023) sums[blockIdx.x] = sm[tid];
}

__global__ void scan2_kernel(int* __restrict__ sums, int n)
{
    __shared__ int sm[128];
    const int tid = threadIdx.x;
    const int v = (tid < n) ? sums[tid] : 0;
    sm[tid] = v;
    __syncthreads();
    for (int off = 1; off < 128; off <<= 1) {
        int t = (tid >= off) ? sm[tid - off] : 0;
        __syncthreads();
        sm[tid] += t;
        __syncthreads();
    }
    if (tid < n) sums[tid] = sm[tid] - v;
}

__global__ void scan3_kernel(int* __restrict__ rp, const int* __restrict__ sums,
                             int* __restrict__ cursor, int n, int E)
{
    int i = blockIdx.x * blockDim.x + threadIdx.x;
    if (i < n) {
        int v = rp[i] + sums[i >> 10];
        rp[i] = v;
        cursor[i] = v;
    }
    if (i == 0) rp[n] = E;
}

__global__ void fill_kernel(const int* __restrict__ ei, int E,
                            int* __restrict__ cursor, int* __restrict__ esrc)
{
    int e = blockIdx.x * blockDim.x + threadIdx.x;
    if (e < E) {
        int d = ei[E + e];
        int p = atomicAdd(&cursor[d], 1);
        esrc[p] = ei[e];
    }
}

// ---- finalize: h[v] = l2norm(relu([z1[v]+b2 | sum_{src->v} z2[src] + b3])),
// written as (hi,lo) f16 pairs. One wave per node; lane owns cols {2l,2l+1}.
__global__ void fin_kernel(const float* __restrict__ z, const int* __restrict__ rp,
                           const int* __restrict__ esrc,
                           const float* __restrict__ b2, const float* __restrict__ b3,
                           unsigned* __restrict__ hp, int M)
{
    const int gid  = blockIdx.x * blockDim.x + threadIdx.x;
    const int v    = gid >> 6;
    const int lane = gid & 63;
    if (v >= M) return;
    const int beg = rp[v], end = rp[v + 1];

    float2 a0 = {0.f, 0.f}, a1 = {0.f, 0.f};
    int j = beg;
    for (; j + 1 < end; j += 2) {
        const int s0 = esrc[j], s1 = esrc[j + 1];
        const float2 g0 = *(const float2*)&z[(size_t)s0 * DIM + 128 + lane * 2];
        const float2 g1 = *(const float2*)&z[(size_t)s1 * DIM + 128 + lane * 2];
        a0.x += g0.x; a0.y += g0.y;
        a1.x += g1.x; a1.y += g1.y;
    }
    if (j < end) {
        const int s0 = esrc[j];
        const float2 g0 = *(const float2*)&z[(size_t)s0 * DIM + 128 + lane * 2];
        a0.x += g0.x; a0.y += g0.y;
    }
    a0.x += a1.x; a0.y += a1.y;

    const float2 z1 = *(const float2*)&z[(size_t)v * DIM + lane * 2];
    const float2 v2 = *(const float2*)&b2[lane * 2];
    const float2 v3 = *(const float2*)&b3[lane * 2];
    float u1x = fmaxf(z1.x + v2.x, 0.f), u1y = fmaxf(z1.y + v2.y, 0.f);
    float u2x = fmaxf(a0.x + v3.x, 0.f), u2y = fmaxf(a0.y + v3.y, 0.f);

    float ss = u1x * u1x + u1y * u1y + u2x * u2x + u2y * u2y;
    #pragma unroll
    for (int off = 32; off > 0; off >>= 1) ss += __shfl_xor(ss, off);
    const float inv = 1.0f / sqrtf(ss);

    uint2 p1; p1.x = pack_pair(u1x * inv); p1.y = pack_pair(u1y * inv);
    uint2 p2; p2.x = pack_pair(u2x * inv); p2.y = pack_pair(u2y * inv);
    *(uint2*)&hp[(size_t)v * DIM + lane * 2]       = p1;
    *(uint2*)&hp[(size_t)v * DIM + 128 + lane * 2] = p2;
}

// ------------------------- launch -------------------------

extern "C" void kernel_launch(void* const* d_in, const int* in_sizes, int n_in,
                              void* d_out, int out_size, void* d_ws, size_t ws_size,
                              hipStream_t stream)
{
    const float* x   = (const float*)d_in[0];
    const int*   ei  = (const int*)d_in[1];
    const float* W1  = (const float*)d_in[2];
    const float* b1  = (const float*)d_in[3];
    const float* W2  = (const float*)d_in[4];
    const float* b2  = (const float*)d_in[5];
    const float* W3  = (const float*)d_in[6];
    const float* b3  = (const float*)d_in[7];
    const float* Wd1 = (const float*)d_in[8];
    const float* bd1 = (const float*)d_in[9];
    const float* Wd2 = (const float*)d_in[10];
    const float* bd2 = (const float*)d_in[11];
    float* out = (float*)d_out;

    const int M = in_sizes[0] / DIM;   // 100000
    const int E = in_sizes[1] / 2;     // 1600000

    unsigned* hp  = (unsigned*)d_ws;                  // M*256 u32 (hi,lo) pairs
    float*    z   = (float*)(hp + (size_t)M * DIM);   // M*256 f32
    int*   rp     = (int*)(z + (size_t)M * DIM);      // M+1
    int*   cursor = rp + (M + 1);                     // M
    int*   esrc   = cursor + M;                       // E
    int*   sums   = esrc + E;                         // <=128

    hipMemsetAsync(cursor, 0, sizeof(int) * M, stream);

    const int gb  = (M + BM - 1) / BM;
    const int eb  = (E + 255) / 256;
    const int nb1 = (M + 1023) / 1024;
    const int wb  = (M * 64 + 255) / 256;

    // CSR build
    hist_kernel<<<eb, 256, 0, stream>>>(ei, E, cursor);
    scan1_kernel<<<nb1, 1024, 0, stream>>>(cursor, M, rp, sums);
    scan2_kernel<<<1, 128, 0, stream>>>(sums, nb1);
    scan3_kernel<<<(M + 255) / 256, 256, 0, stream>>>(rp, sums, cursor, M, E);
    fill_kernel<<<eb, 256, 0, stream>>>(ei, E, cursor, esrc);

    // layer 1: h = l2norm(relu(x @ W1^T + b1)), fp32 A split in staging
    gemm_mfma<0, 1><<<gb, 256, 0, stream>>>(
        x, W1, W1 + 128 * DIM, b1, b1 + 128, hp, nullptr, nullptr, nullptr, M);

    // 2 message-passing layers
    for (int it = 0; it < 2; ++it) {
        gemm_mfma<1, 0><<<gb, 256, 0, stream>>>(
            hp, W2, W3, nullptr, nullptr, z, nullptr, nullptr, nullptr, M);
        fin_kernel<<<wb, 256, 0, stream>>>(z, rp, esrc, b2, b3, hp, M);
    }

    // head: out = relu(h @ Wd1^T + bd1) @ Wd2^T + bd2
    gemm_mfma<1, 2><<<gb, 256, 0, stream>>>(
        hp, Wd1, Wd1 + 128 * DIM, bd1, bd1 + 128, nullptr, Wd2, bd2, out, M);
}

// Round 4
// 733.889 us; speedup vs baseline: 2.4025x; 1.1887x over previous
//
#include <hip/hip_runtime.h>
#include <math.h>

// ---------------------------------------------------------------------------
// DQNNet GNN, f16x3 split-precision MFMA GEMMs (error ~2^-22, fp32-equivalent).
//   h = l2norm(relu(x @ W1^T + b1))            [gemm_l1, + fused edge histogram]
//   2x: z = h @ [W2;W3]^T                      [gemm_z, first fused with CSR fill]
//       h = l2norm(relu([z1+b2 | segsum(z2[src])+b3]))   [fin]
//   out = relu(h @ Wd1^T + bd1) @ Wd2^T + bd2  [gemm_head, matvec fused]
// h stored as (hi,lo) f16 pairs packed in u32 (same bytes as fp32).
// ---------------------------------------------------------------------------

typedef _Float16 f16x8 __attribute__((ext_vector_type(8)));
typedef float    f32x16 __attribute__((ext_vector_type(16)));

constexpr int DIM = 256;
constexpr int BM  = 128;
constexpr int BK  = 32;    // K-slice per staged tile
constexpr int SA  = 40;    // padded LDS row stride (f16)
constexpr int SW  = 40;

__device__ __forceinline__ unsigned pk_hi2(float a, float b) {
    unsigned short ha = __builtin_bit_cast(unsigned short, (_Float16)a);
    unsigned short hb = __builtin_bit_cast(unsigned short, (_Float16)b);
    return (unsigned)ha | ((unsigned)hb << 16);
}
__device__ __forceinline__ unsigned pk_lo2(float a, float b) {
    _Float16 ha = (_Float16)a, hb = (_Float16)b;
    unsigned short la = __builtin_bit_cast(unsigned short, (_Float16)(a - (float)ha));
    unsigned short lb = __builtin_bit_cast(unsigned short, (_Float16)(b - (float)hb));
    return (unsigned)la | ((unsigned)lb << 16);
}
__device__ __forceinline__ unsigned pack_pair(float v) {
    _Float16 hi = (_Float16)v;
    _Float16 lo = (_Float16)(v - (float)hi);
    return (unsigned)__builtin_bit_cast(unsigned short, hi)
         | ((unsigned)__builtin_bit_cast(unsigned short, lo) << 16);
}

// AMODE: 0 = A is fp32 (split during staging); 1 = A is (hi,lo)-pair u32.
// EPI:   0 = raw fp32 z; 1 = bias+relu+l2norm -> pair; 2 = bias+relu+matvec.
template <int AMODE, int EPI>
__device__ __forceinline__
void gemm_body(const void* __restrict__ Av,
               const float* __restrict__ WA, const float* __restrict__ WB,
               const float* __restrict__ bA, const float* __restrict__ bB,
               void* __restrict__ outv,
               const float* __restrict__ wd2, const float* __restrict__ bd2,
               float* __restrict__ out1, int M)
{
    // LDS: As_hi[128][40] As_lo[128][40] Ws_hi[256][40] Ws_lo[256][40] = 60 KB
    __shared__ __align__(16) _Float16 smem[30720];
    _Float16* As_hi = smem;
    _Float16* As_lo = smem + 5120;
    _Float16* Ws_hi = smem + 10240;
    _Float16* Ws_lo = smem + 20480;

    const int tid  = threadIdx.x;
    const int lane = tid & 63;
    const int w    = tid >> 6;
    const int rh   = w >> 1;
    const int ch   = w & 1;
    const int l31  = lane & 31;
    const int lh   = lane >> 5;
    const int bm0  = blockIdx.x * BM;

    const unsigned* Au = (const unsigned*)Av;
    const int srow = tid >> 3;
    const int sch  = (tid & 7) * 4;

    uint4  pa[4];
    float4 pw[8];

    auto fetchA = [&](int t) {
        const int k0 = t * BK;
        #pragma unroll
        for (int i = 0; i < 4; ++i) {
            const int gr = bm0 + srow + 32 * i;
            uint4 v = {0u, 0u, 0u, 0u};
            if (gr < M) v = *(const uint4*)&Au[(size_t)gr * 256 + k0 + sch];
            pa[i] = v;
        }
    };
    auto fetchW = [&](int t) {
        const int k0 = t * BK;
        #pragma unroll
        for (int i = 0; i < 8; ++i) {
            const int r = srow + 32 * i;
            const float* src = (r < 128) ? &WA[(size_t)r * 256]
                                         : &WB[(size_t)(r - 128) * 256];
            pw[i] = *(const float4*)&src[k0 + sch];
        }
    };
    auto stageA = [&]() {
        #pragma unroll
        for (int i = 0; i < 4; ++i) {
            const int r = srow + 32 * i;
            unsigned h0, h1, l0, l1;
            if (AMODE == 0) {
                const float x0 = __builtin_bit_cast(float, pa[i].x);
                const float x1 = __builtin_bit_cast(float, pa[i].y);
                const float x2 = __builtin_bit_cast(float, pa[i].z);
                const float x3 = __builtin_bit_cast(float, pa[i].w);
                h0 = pk_hi2(x0, x1); h1 = pk_hi2(x2, x3);
                l0 = pk_lo2(x0, x1); l1 = pk_lo2(x2, x3);
            } else {
                h0 = __builtin_amdgcn_perm(pa[i].y, pa[i].x, 0x05040100u);
                l0 = __builtin_amdgcn_perm(pa[i].y, pa[i].x, 0x07060302u);
                h1 = __builtin_amdgcn_perm(pa[i].w, pa[i].z, 0x05040100u);
                l1 = __builtin_amdgcn_perm(pa[i].w, pa[i].z, 0x07060302u);
            }
            uint2 th; th.x = h0; th.y = h1;
            uint2 tl; tl.x = l0; tl.y = l1;
            *(uint2*)&As_hi[r * SA + sch] = th;
            *(uint2*)&As_lo[r * SA + sch] = tl;
        }
    };
    auto stageW = [&]() {
        #pragma unroll
        for (int i = 0; i < 8; ++i) {
            const int r = srow + 32 * i;
            uint2 th; th.x = pk_hi2(pw[i].x, pw[i].y); th.y = pk_hi2(pw[i].z, pw[i].w);
            uint2 tl; tl.x = pk_lo2(pw[i].x, pw[i].y); tl.y = pk_lo2(pw[i].z, pw[i].w);
            *(uint2*)&Ws_hi[r * SW + sch] = th;
            *(uint2*)&Ws_lo[r * SW + sch] = tl;
        }
    };

    f32x16 acc[2][4];
    #pragma unroll
    for (int tr = 0; tr < 2; ++tr)
        #pragma unroll
        for (int tc = 0; tc < 4; ++tc)
            #pragma unroll
            for (int i = 0; i < 16; ++i) acc[tr][tc][i] = 0.0f;

    fetchA(0); fetchW(0);

    #pragma unroll 1
    for (int t = 0; t < DIM / BK; ++t) {
        stageA(); stageW();
        __syncthreads();
        if (t < DIM / BK - 1) { fetchA(t + 1); fetchW(t + 1); }

        #pragma unroll
        for (int ks = 0; ks < 2; ++ks) {
            f16x8 ah[2], al[2], wh[4], wl[4];
            #pragma unroll
            for (int tr = 0; tr < 2; ++tr) {
                const int off = (rh * 64 + tr * 32 + l31) * SA + ks * 16 + lh * 8;
                ah[tr] = *(const f16x8*)&As_hi[off];
                al[tr] = *(const f16x8*)&As_lo[off];
            }
            #pragma unroll
            for (int tc = 0; tc < 4; ++tc) {
                const int off = (ch * 128 + tc * 32 + l31) * SW + ks * 16 + lh * 8;
                wh[tc] = *(const f16x8*)&Ws_hi[off];
                wl[tc] = *(const f16x8*)&Ws_lo[off];
            }
            #pragma unroll
            for (int tr = 0; tr < 2; ++tr)
                #pragma unroll
                for (int tc = 0; tc < 4; ++tc) {
                    acc[tr][tc] = __builtin_amdgcn_mfma_f32_32x32x16_f16(ah[tr], wh[tc], acc[tr][tc], 0, 0, 0);
                    acc[tr][tc] = __builtin_amdgcn_mfma_f32_32x32x16_f16(ah[tr], wl[tc], acc[tr][tc], 0, 0, 0);
                    acc[tr][tc] = __builtin_amdgcn_mfma_f32_32x32x16_f16(al[tr], wh[tc], acc[tr][tc], 0, 0, 0);
                }
        }
        __syncthreads();
    }

    // C/D layout (32x32): col = lane&31, row = (reg&3) + 8*(reg>>2) + 4*(lane>>5)

    if (EPI == 0) {
        float* z = (float*)outv;
        #pragma unroll
        for (int tr = 0; tr < 2; ++tr)
            #pragma unroll
            for (int i = 0; i < 16; ++i) {
                const int r  = rh * 64 + tr * 32 + 4 * lh + (i & 3) + 8 * (i >> 2);
                const int gr = bm0 + r;
                if (gr < M) {
                    #pragma unroll
                    for (int tc = 0; tc < 4; ++tc)
                        z[(size_t)gr * 256 + ch * 128 + tc * 32 + l31] = acc[tr][tc][i];
                }
            }
        return;
    }

    {
        float bias[4];
        #pragma unroll
        for (int tc = 0; tc < 4; ++tc)
            bias[tc] = (ch ? bB : bA)[tc * 32 + l31];
        #pragma unroll
        for (int tr = 0; tr < 2; ++tr)
            #pragma unroll
            for (int tc = 0; tc < 4; ++tc)
                #pragma unroll
                for (int i = 0; i < 16; ++i)
                    acc[tr][tc][i] = fmaxf(acc[tr][tc][i] + bias[tc], 0.0f);
    }

    float* red = (float*)smem;

    if (EPI == 1) {
        float ss[2][16];
        #pragma unroll
        for (int tr = 0; tr < 2; ++tr)
            #pragma unroll
            for (int i = 0; i < 16; ++i) {
                float s = 0.f;
                #pragma unroll
                for (int tc = 0; tc < 4; ++tc) s += acc[tr][tc][i] * acc[tr][tc][i];
                #pragma unroll
                for (int m = 1; m < 32; m <<= 1) s += __shfl_xor(s, m);
                ss[tr][i] = s;
            }
        const int j  = l31;
        const int ji = j & 15, jt = j >> 4;
        red[ch * 128 + rh * 64 + jt * 32 + 4 * lh + (ji & 3) + 8 * (ji >> 2)] = ss[jt][ji];
        __syncthreads();

        unsigned* hp = (unsigned*)outv;
        #pragma unroll
        for (int tr = 0; tr < 2; ++tr)
            #pragma unroll
            for (int i = 0; i < 16; ++i) {
                const int rl = rh * 64 + tr * 32 + 4 * lh + (i & 3) + 8 * (i >> 2);
                const float inv = 1.0f / sqrtf(red[rl] + red[128 + rl]);
                const int gr = bm0 + rl;
                if (gr < M) {
                    #pragma unroll
                    for (int tc = 0; tc < 4; ++tc)
                        hp[(size_t)gr * 256 + ch * 128 + tc * 32 + l31] =
                            pack_pair(acc[tr][tc][i] * inv);
                }
            }
        return;
    }

    // EPI == 2: fused head matvec
    {
        float wv[4];
        #pragma unroll
        for (int tc = 0; tc < 4; ++tc) wv[tc] = wd2[ch * 128 + tc * 32 + l31];
        float dd[2][16];
        #pragma unroll
        for (int tr = 0; tr < 2; ++tr)
            #pragma unroll
            for (int i = 0; i < 16; ++i) {
                float s = 0.f;
                #pragma unroll
                for (int tc = 0; tc < 4; ++tc) s += acc[tr][tc][i] * wv[tc];
                #pragma unroll
                for (int m = 1; m < 32; m <<= 1) s += __shfl_xor(s, m);
                dd[tr][i] = s;
            }
        const int j  = l31;
        const int ji = j & 15, jt = j >> 4;
        red[ch * 128 + rh * 64 + jt * 32 + 4 * lh + (ji & 3) + 8 * (ji >> 2)] = dd[jt][ji];
        __syncthreads();
        if (tid < 128) {
            const int gr = bm0 + tid;
            if (gr < M) out1[gr] = red[tid] + red[128 + tid] + bd2[0];
        }
    }
}

// ---- layer-1 GEMM with fused edge histogram (extra blocks past gb) ----
__global__ __launch_bounds__(256, 2)
void gemm_l1(const void* __restrict__ Av,
             const float* __restrict__ WA, const float* __restrict__ WB,
             const float* __restrict__ bA, const float* __restrict__ bB,
             void* __restrict__ outv, int M, int gb,
             const int* __restrict__ ei, int E, int* __restrict__ cnt)
{
    if ((int)blockIdx.x < gb) {
        gemm_body<0, 1>(Av, WA, WB, bA, bB, outv, nullptr, nullptr, nullptr, M);
    } else {
        const int base = ((int)blockIdx.x - gb) * 1024 + threadIdx.x;
        #pragma unroll
        for (int k = 0; k < 4; ++k) {
            const int e = base + k * 256;
            if (e < E) atomicAdd(&cnt[ei[E + e]], 1);
        }
    }
}

// ---- z GEMM; first instance fuses the CSR fill (extra blocks past gb) ----
template <int DO_FILL>
__global__ __launch_bounds__(256, 2)
void gemm_z(const void* __restrict__ Av,
            const float* __restrict__ WA, const float* __restrict__ WB,
            void* __restrict__ outv, int M, int gb,
            const int* __restrict__ ei, int E,
            int* __restrict__ cursor, int* __restrict__ esrc)
{
    if ((int)blockIdx.x < gb) {
        gemm_body<1, 0>(Av, WA, WB, nullptr, nullptr, outv, nullptr, nullptr, nullptr, M);
    } else if (DO_FILL) {
        const int base = ((int)blockIdx.x - gb) * 1024 + threadIdx.x;
        #pragma unroll
        for (int k = 0; k < 4; ++k) {
            const int e = base + k * 256;
            if (e < E) {
                int d = ei[E + e];
                int p = atomicAdd(&cursor[d], 1);
                esrc[p] = ei[e];
            }
        }
    }
}

__global__ __launch_bounds__(256, 2)
void gemm_head(const void* __restrict__ Av,
               const float* __restrict__ WA, const float* __restrict__ WB,
               const float* __restrict__ bA, const float* __restrict__ bB,
               const float* __restrict__ wd2, const float* __restrict__ bd2,
               float* __restrict__ out1, int M)
{
    gemm_body<1, 2>(Av, WA, WB, bA, bB, nullptr, wd2, bd2, out1, M);
}

// ------------------------- scans -------------------------

__global__ void scan1_kernel(const int* __restrict__ cnt, int n,
                             int* __restrict__ rp, int* __restrict__ sums)
{
    __shared__ int sm[1024];
    const int tid = threadIdx.x;
    const int i = blockIdx.x * 1024 + tid;
    const int v = (i < n) ? cnt[i] : 0;
    sm[tid] = v;
    __syncthreads();
    for (int off = 1; off < 1024; off <<= 1) {
        int t = (tid >= off) ? sm[tid - off] : 0;
        __syncthreads();
        sm[tid] += t;
        __syncthreads();
    }
    if (i < n) rp[i] = sm[tid] - v;
    if (tid == 1023) sums[blockIdx.x] = sm[tid];
}

__global__ void scan2_kernel(int* __restrict__ sums, int n)
{
    __shared__ int sm[128];
    const int tid = threadIdx.x;
    const int v = (tid < n) ? sums[tid] : 0;
    sm[tid] = v;
    __syncthreads();
    for (int off = 1; off < 128; off <<= 1) {
        int t = (tid >= off) ? sm[tid - off] : 0;
        __syncthreads();
        sm[tid] += t;
        __syncthreads();
    }
    if (tid < n) sums[tid] = sm[tid] - v;
}

__global__ void scan3_kernel(int* __restrict__ rp, const int* __restrict__ sums,
                             int* __restrict__ cursor, int n, int E)
{
    int i = blockIdx.x * blockDim.x + threadIdx.x;
    if (i < n) {
        int v = rp[i] + sums[i >> 10];
        rp[i] = v;
        cursor[i] = v;
    }
    if (i == 0) rp[n] = E;
}

// ---- finalize: h[v] = l2norm(relu([z1[v]+b2 | segsum(z2[src])+b3])) ----
// One wave per node. Edge indices preloaded 64-wide (one coalesced load),
// broadcast via v_readlane -> gather addresses come from the SCALAR unit
// (global_load_dwordx2 v, voff, s[saddr]); 4 independent accumulators keep
// 4 gathers of 512 B in flight per wave.
__global__ __launch_bounds__(256)
void fin_kernel(const float* __restrict__ z, const int* __restrict__ rp,
                const int* __restrict__ esrc,
                const float* __restrict__ b2, const float* __restrict__ b3,
                unsigned* __restrict__ hp, int M)
{
    const int v    = blockIdx.x * 4 + (threadIdx.x >> 6);
    const int lane = threadIdx.x & 63;
    if (v >= M) return;
    const int beg = rp[v], end = rp[v + 1];
    const int deg = end - beg;

    const float2 z1 = *(const float2*)&z[(size_t)v * DIM + lane * 2];
    const float2 c2 = *(const float2*)&b2[lane * 2];
    const float2 c3 = *(const float2*)&b3[lane * 2];

    const float* z2 = z + 128;
    float ax0 = 0.f, ay0 = 0.f, ax1 = 0.f, ay1 = 0.f;
    float ax2 = 0.f, ay2 = 0.f, ax3 = 0.f, ay3 = 0.f;

    for (int base = 0; base < deg; base += 64) {
        const int cnt = min(64, deg - base);
        int myidx = 0;
        if (lane < cnt) myidx = esrc[beg + base + lane];
        int j = 0;
        for (; j + 3 < cnt; j += 4) {
            const int s0 = __builtin_amdgcn_readlane(myidx, j);
            const int s1 = __builtin_amdgcn_readlane(myidx, j + 1);
            const int s2 = __builtin_amdgcn_readlane(myidx, j + 2);
            const int s3 = __builtin_amdgcn_readlane(myidx, j + 3);
            const float2 g0 = *(const float2*)&z2[(size_t)s0 * DIM + lane * 2];
            const float2 g1 = *(const float2*)&z2[(size_t)s1 * DIM + lane * 2];
            const float2 g2 = *(const float2*)&z2[(size_t)s2 * DIM + lane * 2];
            const float2 g3 = *(const float2*)&z2[(size_t)s3 * DIM + lane * 2];
            ax0 += g0.x; ay0 += g0.y;
            ax1 += g1.x; ay1 += g1.y;
            ax2 += g2.x; ay2 += g2.y;
            ax3 += g3.x; ay3 += g3.y;
        }
        for (; j < cnt; ++j) {
            const int s0 = __builtin_amdgcn_readlane(myidx, j);
            const float2 g0 = *(const float2*)&z2[(size_t)s0 * DIM + lane * 2];
            ax0 += g0.x; ay0 += g0.y;
        }
    }
    const float sx = (ax0 + ax1) + (ax2 + ax3);
    const float sy = (ay0 + ay1) + (ay2 + ay3);

    const float u1x = fmaxf(z1.x + c2.x, 0.f), u1y = fmaxf(z1.y + c2.y, 0.f);
    const float u2x = fmaxf(sx + c3.x, 0.f),  u2y = fmaxf(sy + c3.y, 0.f);

    float ss = u1x * u1x + u1y * u1y + u2x * u2x + u2y * u2y;
    #pragma unroll
    for (int off = 32; off > 0; off >>= 1) ss += __shfl_xor(ss, off);
    const float inv = 1.0f / sqrtf(ss);

    uint2 p1; p1.x = pack_pair(u1x * inv); p1.y = pack_pair(u1y * inv);
    uint2 p2; p2.x = pack_pair(u2x * inv); p2.y = pack_pair(u2y * inv);
    *(uint2*)&hp[(size_t)v * DIM + lane * 2]       = p1;
    *(uint2*)&hp[(size_t)v * DIM + 128 + lane * 2] = p2;
}

// ------------------------- launch -------------------------

extern "C" void kernel_launch(void* const* d_in, const int* in_sizes, int n_in,
                              void* d_out, int out_size, void* d_ws, size_t ws_size,
                              hipStream_t stream)
{
    const float* x   = (const float*)d_in[0];
    const int*   ei  = (const int*)d_in[1];
    const float* W1  = (const float*)d_in[2];
    const float* b1  = (const float*)d_in[3];
    const float* W2  = (const float*)d_in[4];
    const float* b2  = (const float*)d_in[5];
    const float* W3  = (const float*)d_in[6];
    const float* b3  = (const float*)d_in[7];
    const float* Wd1 = (const float*)d_in[8];
    const float* bd1 = (const float*)d_in[9];
    const float* Wd2 = (const float*)d_in[10];
    const float* bd2 = (const float*)d_in[11];
    float* out = (float*)d_out;

    const int M = in_sizes[0] / DIM;   // 100000
    const int E = in_sizes[1] / 2;     // 1600000

    unsigned* hp  = (unsigned*)d_ws;                  // M*256 u32 (hi,lo) pairs
    float*    z   = (float*)(hp + (size_t)M * DIM);   // M*256 f32
    int*   rp     = (int*)(z + (size_t)M * DIM);      // M+1
    int*   cursor = rp + (M + 1);                     // M
    int*   esrc   = cursor + M;                       // E
    int*   sums   = esrc + E;                         // <=128

    hipMemsetAsync(cursor, 0, sizeof(int) * M, stream);

    const int gb  = (M + BM - 1) / BM;       // 782 gemm blocks
    const int hb  = (E + 1023) / 1024;       // 1563 edge blocks (4 edges/thread)
    const int nb1 = (M + 1023) / 1024;
    const int fb  = (M + 3) / 4;             // fin: 4 nodes (waves) per block

    // layer 1 GEMM + edge histogram (overlapped in one grid)
    gemm_l1<<<gb + hb, 256, 0, stream>>>(
        x, W1, W1 + 128 * DIM, b1, b1 + 128, hp, M, gb, ei, E, cursor);

    // prefix-sum -> rp, reset cursor to offsets
    scan1_kernel<<<nb1, 1024, 0, stream>>>(cursor, M, rp, sums);
    scan2_kernel<<<1, 128, 0, stream>>>(sums, nb1);
    scan3_kernel<<<(M + 255) / 256, 256, 0, stream>>>(rp, sums, cursor, M, E);

    // z GEMM #1 + CSR fill (overlapped), then finalize
    gemm_z<1><<<gb + hb, 256, 0, stream>>>(hp, W2, W3, z, M, gb, ei, E, cursor, esrc);
    fin_kernel<<<fb, 256, 0, stream>>>(z, rp, esrc, b2, b3, hp, M);

    // z GEMM #2, finalize
    gemm_z<0><<<gb, 256, 0, stream>>>(hp, W2, W3, z, M, gb, nullptr, 0, nullptr, nullptr);
    fin_kernel<<<fb, 256, 0, stream>>>(z, rp, esrc, b2, b3, hp, M);

    // head: out = relu(h @ Wd1^T + bd1) @ Wd2^T + bd2
    gemm_head<<<gb, 256, 0, stream>>>(
        hp, Wd1, Wd1 + 128 * DIM, bd1, bd1 + 128, Wd2, bd2, out, M);
}